// Round 2
// baseline (281.472 us; speedup 1.0000x reference)
//
#include <hip/hip_runtime.h>

#define SIZE 1024
#define MM 10
#define NTERMS 10
#define RPB 16         // batch rows resident per block
#define NTHREADS 256   // 128 col-threads x 2 row-sets
#define W 8            // columns per thread

typedef __attribute__((ext_vector_type(8))) _Float16 h8;   // 16B: one ds_read_b128
typedef __attribute__((ext_vector_type(4))) _Float16 h4;   // 8B

__device__ __forceinline__ float4 ldq(const float* p) { return *(const float4*)p; }

// ---------------------------------------------------------------------------
// fp16-in-LDS butterfly: intermediate rows stored as fp16 (halves LDS bytes),
// W=8 cols/thread so near taps (d<=8) collapse into 2 octet reads.
// 16 LDS ops / 8 cols / row-term vs 36 for the fp32 W=4 version (2.25x on the
// bound DS pipe). All arithmetic (coefs + accumulation) stays fp32; only the
// 9 inter-term row snapshots + the initial x staging are rounded to fp16 (RTN).
// Final term writes fp32 directly to global (no 10th rounding).
// ---------------------------------------------------------------------------
__global__ __launch_bounds__(NTHREADS, 2)
void butterfly_h16(const float* __restrict__ x,
                   const float* __restrict__ diag,
                   const float* __restrict__ subpad,
                   const float* __restrict__ suppad,
                   const float* __restrict__ logit,
                   float* __restrict__ out)
{
    __shared__ _Float16 buf[2][RPB][SIZE];   // 2*16*1024*2B = 64 KB -> 2 blocks/CU

    const int tid = threadIdx.x;
    const int ct  = tid & 127;        // column group: cols [8*ct, 8*ct+8)
    const int rs  = tid >> 7;         // row set: rows [8*rs, 8*rs+8)
    const int s0  = ct * W;
    const int r0  = rs * 8;
    const long rowbase = (long)blockIdx.x * RPB;

    // ---- stage x: fp32 global -> fp16 LDS (coalesced float4, RTN cvt) ----
    {
        const int sc = tid * 4;       // 256 threads x 4 cols = 1024
        #pragma unroll
        for (int r = 0; r < RPB; ++r) {
            const float4 v = ldq(x + (rowbase + r) * SIZE + sc);
            h4 h;
            h[0] = (_Float16)v.x; h[1] = (_Float16)v.y;
            h[2] = (_Float16)v.z; h[3] = (_Float16)v.w;
            *(h4*)&buf[0][r][sc] = h;
        }
    }
    __syncthreads();

    int cur = 0;
    for (int t = 0; t < NTERMS; ++t) {
        const int i = NTERMS - 1 - t;     // reference applies prob[9] first

        // ---- softmax over logit[i][:] (10 values, redundant per thread) ----
        float lg[MM];
        float mx = -3.4e38f;
        #pragma unroll
        for (int j = 0; j < MM; ++j) { lg[j] = logit[i * MM + j]; mx = fmaxf(mx, lg[j]); }
        float ssum = 0.f;
        #pragma unroll
        for (int j = 0; j < MM; ++j) { lg[j] = __expf(lg[j] - mx); ssum += lg[j]; }
        const float inv = 1.0f / ssum;

        // ---- prob-weighted coefficients for this thread's 8 columns (fp32) ----
        float D[W];
        float Wsb[MM][W], Wsp[MM][W];
        #pragma unroll
        for (int k = 0; k < W; ++k) D[k] = 0.f;
        #pragma unroll
        for (int j = 0; j < MM; ++j) {
            const float pj = lg[j] * inv;
            const float4 dg0 = ldq(diag   + j * SIZE + s0);
            const float4 dg1 = ldq(diag   + j * SIZE + s0 + 4);
            const float4 sb0 = ldq(subpad + j * SIZE + s0);
            const float4 sb1 = ldq(subpad + j * SIZE + s0 + 4);
            const float4 sp0 = ldq(suppad + j * SIZE + s0);
            const float4 sp1 = ldq(suppad + j * SIZE + s0 + 4);
            D[0] = fmaf(pj, dg0.x, D[0]); D[1] = fmaf(pj, dg0.y, D[1]);
            D[2] = fmaf(pj, dg0.z, D[2]); D[3] = fmaf(pj, dg0.w, D[3]);
            D[4] = fmaf(pj, dg1.x, D[4]); D[5] = fmaf(pj, dg1.y, D[5]);
            D[6] = fmaf(pj, dg1.z, D[6]); D[7] = fmaf(pj, dg1.w, D[7]);
            Wsb[j][0] = pj * sb0.x; Wsb[j][1] = pj * sb0.y;
            Wsb[j][2] = pj * sb0.z; Wsb[j][3] = pj * sb0.w;
            Wsb[j][4] = pj * sb1.x; Wsb[j][5] = pj * sb1.y;
            Wsb[j][6] = pj * sb1.z; Wsb[j][7] = pj * sb1.w;
            Wsp[j][0] = pj * sp0.x; Wsp[j][1] = pj * sp0.y;
            Wsp[j][2] = pj * sp0.z; Wsp[j][3] = pj * sp0.w;
            Wsp[j][4] = pj * sp1.x; Wsp[j][5] = pj * sp1.y;
            Wsp[j][6] = pj * sp1.z; Wsp[j][7] = pj * sp1.w;
        }

        const bool last = (t == NTERMS - 1);

        // ---- apply 21-tap operator to this thread's 8 rows ----
        // OOB taps: clamp the LDS address; matching coefs are exactly zero
        // (subpad zeroed for s<d, suppad zeroed for s>=SIZE-d; s0 is a
        // multiple of 8 and far d's are multiples of 16, so a clamped octet
        // has ALL-zero coefs; near-tap clamps pair with zeroed edge coefs).
        for (int r = r0; r < r0 + 8; ++r) {
            const _Float16* row = &buf[cur][r][0];

            const h8 c = *(const h8*)&row[s0];
            const h8 L = *(const h8*)&row[(s0 >= 8)         ? s0 - 8 : 0];
            const h8 R = *(const h8*)&row[(s0 + 8 <= 1016)  ? s0 + 8 : 1016];

            float acc[W];
            #pragma unroll
            for (int k = 0; k < W; ++k) acc[k] = D[k] * (float)c[k];

            // near taps: d = 1,2,4,8  (j = 9,8,7,6) — served by c/L/R
            #pragma unroll
            for (int dl = 0; dl < 4; ++dl) {
                const int d = 1 << dl, j = 9 - dl;
                #pragma unroll
                for (int k = 0; k < W; ++k) {
                    const float sub = (k >= d)    ? (float)c[k - d] : (float)L[k - d + 8];
                    const float sup = (k + d < 8) ? (float)c[k + d] : (float)R[k + d - 8];
                    acc[k] = fmaf(Wsb[j][k], sub, acc[k]);
                    acc[k] = fmaf(Wsp[j][k], sup, acc[k]);
                }
            }

            // far taps: d = 512,256,128,64,32,16  (j = 0..5)
            #pragma unroll
            for (int j = 0; j < 6; ++j) {
                const int d = 512 >> j;
                const h8 Mm = *(const h8*)&row[(s0 >= d)           ? s0 - d : 0];
                const h8 Pp = *(const h8*)&row[(s0 + d <= 1016)    ? s0 + d : 1016];
                #pragma unroll
                for (int k = 0; k < W; ++k) {
                    acc[k] = fmaf(Wsb[j][k], (float)Mm[k], acc[k]);
                    acc[k] = fmaf(Wsp[j][k], (float)Pp[k], acc[k]);
                }
            }

            if (last) {
                // final term: write fp32 result straight to global (no rounding)
                float* op = out + (rowbase + r) * SIZE + s0;
                *(float4*)op       = make_float4(acc[0], acc[1], acc[2], acc[3]);
                *(float4*)(op + 4) = make_float4(acc[4], acc[5], acc[6], acc[7]);
            } else {
                h8 hv;
                #pragma unroll
                for (int k = 0; k < W; ++k) hv[k] = (_Float16)acc[k];
                *(h8*)&buf[cur ^ 1][r][s0] = hv;
            }
        }
        __syncthreads();   // writes to buf[cur^1] visible before next term
        cur ^= 1;
    }
}

extern "C" void kernel_launch(void* const* d_in, const int* in_sizes, int n_in,
                              void* d_out, int out_size, void* d_ws, size_t ws_size,
                              hipStream_t stream) {
    const float* x      = (const float*)d_in[0];
    const float* diag   = (const float*)d_in[1];
    const float* subpad = (const float*)d_in[2];
    const float* suppad = (const float*)d_in[3];
    const float* logit  = (const float*)d_in[4];
    float* outp = (float*)d_out;

    const int batch = in_sizes[0] / SIZE;      // 8192
    const int nblocks = batch / RPB;           // 512

    butterfly_h16<<<dim3(nblocks), dim3(NTHREADS), 0, stream>>>(
        x, diag, subpad, suppad, logit, outp);
}